// Round 6
// baseline (82.934 us; speedup 1.0000x reference)
//
#include <hip/hip_runtime.h>
#include <hip/hip_bf16.h>

#define B 16
#define S 2048
#define VOCAB 32000
#define D_EMB 256
#define D_MODEL 512
#define LN_EPS 1e-5f

using bf16x8 = __attribute__((ext_vector_type(8))) short;
using f32x4  = __attribute__((ext_vector_type(4))) float;

static __device__ __forceinline__ unsigned short f2bf(float f) {
    __hip_bfloat16 h = __float2bfloat16(f);   // RNE
    return *reinterpret_cast<unsigned short*>(&h);
}

static __device__ __forceinline__ bf16x8 pack8(f32x4 v0, f32x4 v1) {
    union { unsigned short us[8]; bf16x8 v; } pk;
    pk.us[0] = f2bf(v0.x); pk.us[1] = f2bf(v0.y);
    pk.us[2] = f2bf(v0.z); pk.us[3] = f2bf(v0.w);
    pk.us[4] = f2bf(v1.x); pk.us[5] = f2bf(v1.y);
    pk.us[6] = f2bf(v1.z); pk.us[7] = f2bf(v1.w);
    return pk.v;
}

// ---------------------------------------------------------------------------
// Kernel A (MFMA): Wk[b][r] = sum_j Wb[r][j] * kemb[b][j],  r = m*256+i.
// One 16-row fragment per wave, grid 2048 x 4 waves -> ~6 waves/SIMD for
// HBM latency hiding (R5 had 2). Wb streamed with NT loads (read-once).
// kemb B-fragments register-resident. A-frag: lane(lr,kg) reads row
// rb+lr, k = step*32+kg*8 (16B). C/D: col=lr=b, row=kg*4+reg.
// ---------------------------------------------------------------------------
__global__ __launch_bounds__(256) void wk_mfma(
    const float* __restrict__ Wb,
    const float* __restrict__ king_table,
    const int* __restrict__ king_id,
    unsigned short* __restrict__ Wk)
{
    const int t    = threadIdx.x;
    const int lane = t & 63;
    const int wave = t >> 6;
    const int lr   = lane & 15;     // b index (B-frag col) / row index (A-frag)
    const int kg   = lane >> 4;     // k-group

    // ---- kemb B-operand fragments, register-resident ----
    const int kid = king_id[lr];
    const float* kp = king_table + (size_t)kid * D_EMB + kg * 8;
    bf16x8 bemb[8];
#pragma unroll
    for (int step = 0; step < 8; ++step) {
        f32x4 v0 = *(const f32x4*)(kp + step * 32);
        f32x4 v1 = *(const f32x4*)(kp + step * 32 + 4);
        bemb[step] = pack8(v0, v1);
    }

    const int rb = (blockIdx.x * 4 + wave) * 16;   // fragment row base
    const float* arow = Wb + (size_t)(rb + lr) * D_EMB + kg * 8;

    f32x4 acc = {};
    // two chunks of 4 K-steps: 8 NT dwordx4 in flight per chunk (~32 VGPR)
#pragma unroll
    for (int ch = 0; ch < 2; ++ch) {
        f32x4 v[8];
#pragma unroll
        for (int u = 0; u < 4; ++u) {
            v[2 * u]     = __builtin_nontemporal_load(
                (const f32x4*)(arow + (ch * 4 + u) * 32));
            v[2 * u + 1] = __builtin_nontemporal_load(
                (const f32x4*)(arow + (ch * 4 + u) * 32 + 4));
        }
#pragma unroll
        for (int u = 0; u < 4; ++u)
            acc = __builtin_amdgcn_mfma_f32_16x16x32_bf16(
                pack8(v[2 * u], v[2 * u + 1]), bemb[ch * 4 + u], acc, 0, 0, 0);
    }

    // lane holds C[kg*4 + r][b=lr], r=0..3 -> 4 consecutive Wk entries
    union { unsigned short us[4]; uint2 q; } st;
    st.us[0] = f2bf(acc[0]); st.us[1] = f2bf(acc[1]);
    st.us[2] = f2bf(acc[2]); st.us[3] = f2bf(acc[3]);
    *(uint2*)(Wk + (size_t)lr * (D_MODEL * D_EMB) + rb + kg * 4) = st.q;
}

// ---------------------------------------------------------------------------
// Kernel B (MFMA): x[b,s,m] = sum_k tok[b,s,k]*Wk[b,m,k] + bb[m]; LN over m.
// grid = (S/32, B) = 1024 blocks, 512 threads = 8 waves (4 blocks/CU target).
// Block tile: 32 s-rows x 512 m-cols (full m-span -> LN block-local).
// Wave w owns m-slice [w*64, w*64+64): M_rep=2, N_rep=4.
// ---------------------------------------------------------------------------
#define SROWS 32

__global__ __launch_bounds__(512) void gemm_ln_mfma(
    const int* __restrict__ seq,
    const int* __restrict__ king_id,
    const float* __restrict__ token_tables,
    const unsigned short* __restrict__ Wk,
    const float* __restrict__ bb,
    const float* __restrict__ gamma,
    const float* __restrict__ beta,
    float* __restrict__ out)
{
    __shared__ unsigned short tokL[SROWS][264];   // 32 x (256+8 pad) bf16
    __shared__ float red_sum[8][SROWS];
    __shared__ float red_sq[8][SROWS];
    __shared__ float stats[2][SROWS];             // [0]=mean, [1]=rstd

    const int b    = blockIdx.y;
    const int s0   = blockIdx.x * SROWS;
    const int t    = threadIdx.x;
    const int lane = t & 63;
    const int wave = t >> 6;
    const int lr   = lane & 15;     // frag row/col index
    const int kg   = lane >> 4;     // k-group (0..3)

    const int kb = king_id[b];
    const float* ttab = token_tables + (size_t)kb * VOCAB * D_EMB;

    // ---- stage gathered tok tile: fp32 global -> bf16 LDS ----
    {
        int row = t >> 4;            // 0..31 (16 threads per row)
        int ck  = (t & 15) * 16;     // k chunk start (16 floats)
        int tokidx = seq[b * S + s0 + row];
        const float4* src = (const float4*)(ttab + (size_t)tokidx * D_EMB + ck);
#pragma unroll
        for (int u = 0; u < 2; ++u) {
            float4 v0 = src[u * 2 + 0];
            float4 v1 = src[u * 2 + 1];
            union { unsigned short us[8]; uint4 q; } pk;
            pk.us[0] = f2bf(v0.x); pk.us[1] = f2bf(v0.y);
            pk.us[2] = f2bf(v0.z); pk.us[3] = f2bf(v0.w);
            pk.us[4] = f2bf(v1.x); pk.us[5] = f2bf(v1.y);
            pk.us[6] = f2bf(v1.z); pk.us[7] = f2bf(v1.w);
            *(uint4*)&tokL[row][ck + u * 8] = pk.q;
        }
    }
    __syncthreads();

    // ---- fragment pointers ----
    const int m0 = wave * 64;                  // wave's m-slice base
    const uint4* aptr[2];
    const uint4* bptr[4];
#pragma unroll
    for (int mf = 0; mf < 2; ++mf)
        aptr[mf] = (const uint4*)&tokL[mf * 16 + lr][kg * 8];
#pragma unroll
    for (int nf = 0; nf < 4; ++nf) {
        int col = m0 + nf * 16 + lr;
        bptr[nf] = (const uint4*)(Wk + ((size_t)(b * D_MODEL + col)) * D_EMB + kg * 8);
    }

    f32x4 acc[2][4] = {};

    // ---- K loop: 8 steps of K=32, fully unrolled ----
#pragma unroll
    for (int step = 0; step < 8; ++step) {
        bf16x8 af[2], bfr[4];
#pragma unroll
        for (int mf = 0; mf < 2; ++mf) {
            uint4 q = aptr[mf][step * 4];
            af[mf] = __builtin_bit_cast(bf16x8, q);
        }
#pragma unroll
        for (int nf = 0; nf < 4; ++nf) {
            uint4 q = bptr[nf][step * 4];
            bfr[nf] = __builtin_bit_cast(bf16x8, q);
        }
#pragma unroll
        for (int mf = 0; mf < 2; ++mf)
#pragma unroll
            for (int nf = 0; nf < 4; ++nf)
                acc[mf][nf] = __builtin_amdgcn_mfma_f32_16x16x32_bf16(
                    af[mf], bfr[nf], acc[mf][nf], 0, 0, 0);
    }

    // ---- epilogue: bias, block-wide LN stats ----
    float bbv[4], gv[4], bv[4];
#pragma unroll
    for (int nf = 0; nf < 4; ++nf) {
        int col = m0 + nf * 16 + lr;
        bbv[nf] = bb[col];
        gv[nf]  = gamma[col];
        bv[nf]  = beta[col];
    }

#pragma unroll
    for (int mf = 0; mf < 2; ++mf) {
#pragma unroll
        for (int r = 0; r < 4; ++r) {
            float sum = 0.0f, sq = 0.0f;
#pragma unroll
            for (int nf = 0; nf < 4; ++nf) {
                float v = acc[mf][nf][r] + bbv[nf];
                acc[mf][nf][r] = v;
                sum += v;
                sq  += v * v;
            }
#pragma unroll
            for (int off = 1; off < 16; off <<= 1) {
                sum += __shfl_xor(sum, off);
                sq  += __shfl_xor(sq, off);
            }
            if (lr == 0) {
                int row = mf * 16 + kg * 4 + r;
                red_sum[wave][row] = sum;
                red_sq[wave][row]  = sq;
            }
        }
    }
    __syncthreads();

    if (t < SROWS) {
        float s = 0.0f, q = 0.0f;
#pragma unroll
        for (int w = 0; w < 8; ++w) { s += red_sum[w][t]; q += red_sq[w][t]; }
        float mean = s * (1.0f / D_MODEL);
        float var  = q * (1.0f / D_MODEL) - mean * mean;
        stats[0][t] = mean;
        stats[1][t] = rsqrtf(var + LN_EPS);
    }
    __syncthreads();

    // ---- normalize + store ----
#pragma unroll
    for (int mf = 0; mf < 2; ++mf) {
#pragma unroll
        for (int r = 0; r < 4; ++r) {
            int row = mf * 16 + kg * 4 + r;
            float mean = stats[0][row];
            float rstd = stats[1][row];
            float* op = out + ((size_t)b * S + s0 + row) * D_MODEL + m0 + lr;
#pragma unroll
            for (int nf = 0; nf < 4; ++nf)
                op[nf * 16] = (acc[mf][nf][r] - mean) * rstd * gv[nf] + bv[nf];
        }
    }
}

// ---------------------------------------------------------------------------
extern "C" void kernel_launch(void* const* d_in, const int* in_sizes, int n_in,
                              void* d_out, int out_size, void* d_ws, size_t ws_size,
                              hipStream_t stream)
{
    const int*   seq          = (const int*)d_in[0];
    const int*   king_id      = (const int*)d_in[1];
    const float* token_tables = (const float*)d_in[2];
    const float* Wb           = (const float*)d_in[3];
    const float* bb           = (const float*)d_in[4];
    const float* king_table   = (const float*)d_in[5];
    const float* gamma        = (const float*)d_in[6];
    const float* beta         = (const float*)d_in[7];
    float* out = (float*)d_out;

    unsigned short* Wk = (unsigned short*)d_ws;   // B*D_MODEL*D_EMB bf16 = 4 MB

    wk_mfma<<<dim3((D_MODEL * D_EMB) / 64), dim3(256), 0, stream>>>(
        Wb, king_table, king_id, Wk);
    gemm_ln_mfma<<<dim3(S / SROWS, B), dim3(512), 0, stream>>>(
        seq, king_id, token_tables, Wk, bb, gamma, beta, out);
}

// Round 7
// 82.665 us; speedup vs baseline: 1.0032x; 1.0032x over previous
//
#include <hip/hip_runtime.h>
#include <hip/hip_bf16.h>

#define B 16
#define S 2048
#define VOCAB 32000
#define D_EMB 256
#define D_MODEL 512
#define LN_EPS 1e-5f

using bf16x8 = __attribute__((ext_vector_type(8))) short;
using f32x4  = __attribute__((ext_vector_type(4))) float;

static __device__ __forceinline__ unsigned short f2bf(float f) {
    __hip_bfloat16 h = __float2bfloat16(f);   // RNE
    return *reinterpret_cast<unsigned short*>(&h);
}

static __device__ __forceinline__ bf16x8 pack8(f32x4 v0, f32x4 v1) {
    union { unsigned short us[8]; bf16x8 v; } pk;
    pk.us[0] = f2bf(v0.x); pk.us[1] = f2bf(v0.y);
    pk.us[2] = f2bf(v0.z); pk.us[3] = f2bf(v0.w);
    pk.us[4] = f2bf(v1.x); pk.us[5] = f2bf(v1.y);
    pk.us[6] = f2bf(v1.z); pk.us[7] = f2bf(v1.w);
    return pk.v;
}

// ---------------------------------------------------------------------------
// Kernel A (MFMA) — EXACT R5 form (measured part of the 68.7 µs config).
// Wk[b][r] = sum_j Wb[r][j] * kemb[b][j]; kemb fragments register-resident;
// Wb rows feed A-fragments straight from global; 64 rows per wave.
// ---------------------------------------------------------------------------
__global__ __launch_bounds__(256) void wk_mfma(
    const float* __restrict__ Wb,
    const float* __restrict__ king_table,
    const int* __restrict__ king_id,
    unsigned short* __restrict__ Wk)
{
    const int t    = threadIdx.x;
    const int lane = t & 63;
    const int wave = t >> 6;
    const int lr   = lane & 15;     // b index (B-frag col) / row index (A-frag)
    const int kg   = lane >> 4;     // k-group

    const int kid = king_id[lr];
    const float* kp = king_table + (size_t)kid * D_EMB + kg * 8;
    bf16x8 bemb[8];
#pragma unroll
    for (int step = 0; step < 8; ++step) {
        f32x4 v0 = *(const f32x4*)(kp + step * 32);
        f32x4 v1 = *(const f32x4*)(kp + step * 32 + 4);
        bemb[step] = pack8(v0, v1);
    }

    const int rbase = (blockIdx.x * 4 + wave) * 64;

#pragma unroll
    for (int mf = 0; mf < 4; ++mf) {
        const float* arow = Wb + (size_t)(rbase + mf * 16 + lr) * D_EMB + kg * 8;
        f32x4 acc = {};
#pragma unroll
        for (int step = 0; step < 8; ++step) {
            f32x4 v0 = *(const f32x4*)(arow + step * 32);
            f32x4 v1 = *(const f32x4*)(arow + step * 32 + 4);
            acc = __builtin_amdgcn_mfma_f32_16x16x32_bf16(
                pack8(v0, v1), bemb[step], acc, 0, 0, 0);
        }
        union { unsigned short us[4]; uint2 q; } st;
        st.us[0] = f2bf(acc[0]); st.us[1] = f2bf(acc[1]);
        st.us[2] = f2bf(acc[2]); st.us[3] = f2bf(acc[3]);
        *(uint2*)(Wk + (size_t)lr * (D_MODEL * D_EMB) + rbase + mf * 16 + kg * 4) = st.q;
    }
}

// ---------------------------------------------------------------------------
// Kernel B (MFMA): x[b,s,m] = sum_k tok[b,s,k]*Wk[b,m,k] + bb[m]; LN over m.
// grid = (S/64, B), 512 threads = 8 waves; tile 64 s x 512 m (LN block-local).
// CHANGE vs R5: Wk B-fragments now come from LDS. K processed in 8 eighths;
// per eighth a 32 KB tile wkq[512 m][32 k] is staged via a T14 split:
//   issue eighth e+1's global loads -> compute eighth e -> barrier ->
//   ds_write e+1 -> barrier.
// wkq m-stride = 64 B (16 dwords): read lanes (lr parity x kg) spread over
// all 32 banks, 8 lanes per 4-bank cluster = full rate; staged writes
// (slot = c*512+t) are lane-consecutive 16B = full rate. No padding needed.
// LDS: 33.8 (tokL) + 32 (wkq) + 4.5 (red) KB = 69.5 KB -> 2 blocks/CU.
// ---------------------------------------------------------------------------
#define TSB 64

__global__ __launch_bounds__(512, 4) void gemm_ln_mfma(
    const int* __restrict__ seq,
    const int* __restrict__ king_id,
    const float* __restrict__ token_tables,
    const unsigned short* __restrict__ Wk,
    const float* __restrict__ bb,
    const float* __restrict__ gamma,
    const float* __restrict__ beta,
    float* __restrict__ out)
{
    __shared__ unsigned short tokL[TSB][264];   // 64 x (256+8 pad) bf16
    __shared__ unsigned short wkq[D_MODEL * 32];// 512 m x 32 k bf16 = 32 KB
    __shared__ float red_sum[8][TSB];
    __shared__ float red_sq[8][TSB];
    __shared__ float stats[2][TSB];

    const int b    = blockIdx.y;
    const int s0   = blockIdx.x * TSB;
    const int t    = threadIdx.x;
    const int lane = t & 63;
    const int wave = t >> 6;
    const int lr   = lane & 15;     // frag row/col index
    const int kg   = lane >> 4;     // k-group (0..3)

    const int kb = king_id[b];
    const float* ttab = token_tables + (size_t)kb * VOCAB * D_EMB;
    const unsigned short* wkb = Wk + (size_t)b * (D_MODEL * D_EMB);

    // staging geometry for wkq: thread t, chunk c -> slot S = c*512 + t;
    // slot S holds Wk row m = S>>2, k-chunk cc = S&3 (8 shorts each)
    const int mrow = t >> 2;
    const int cc   = t & 3;

    // ---- prologue: issue tok-gather loads + wk eighth-0 loads ----
    uint4 wst[4];
#pragma unroll
    for (int c = 0; c < 4; ++c)
        wst[c] = *(const uint4*)(wkb + (size_t)(c * 128 + mrow) * D_EMB + cc * 8);

    {
        int row = t >> 3;            // 0..63
        int ck  = (t & 7) * 32;      // k chunk start (32 floats)
        int tokidx = seq[b * S + s0 + row];
        const float4* src = (const float4*)(ttab + (size_t)tokidx * D_EMB + ck);
#pragma unroll
        for (int u = 0; u < 4; ++u) {
            float4 v0 = src[u * 2 + 0];
            float4 v1 = src[u * 2 + 1];
            union { unsigned short us[8]; uint4 q; } pk;
            pk.us[0] = f2bf(v0.x); pk.us[1] = f2bf(v0.y);
            pk.us[2] = f2bf(v0.z); pk.us[3] = f2bf(v0.w);
            pk.us[4] = f2bf(v1.x); pk.us[5] = f2bf(v1.y);
            pk.us[6] = f2bf(v1.z); pk.us[7] = f2bf(v1.w);
            *(uint4*)&tokL[row][ck + u * 8] = pk.q;
        }
    }
#pragma unroll
    for (int c = 0; c < 4; ++c)
        *(uint4*)&wkq[(c * 512 + t) * 8] = wst[c];
    __syncthreads();

    const int m0 = wave * 64;                  // wave's m-slice base
    f32x4 acc[4][4] = {};

    // ---- K loop over 8 eighths of K=32 ----
#pragma unroll
    for (int e = 0; e < 8; ++e) {
        // T14 issue-early: next eighth's global loads before this MFMA block
        uint4 nst[4];
        if (e < 7) {
#pragma unroll
            for (int c = 0; c < 4; ++c)
                nst[c] = *(const uint4*)(wkb + (size_t)(c * 128 + mrow) * D_EMB
                                         + (e + 1) * 32 + cc * 8);
        }

        bf16x8 af[4], bfr[4];
#pragma unroll
        for (int mf = 0; mf < 4; ++mf) {
            uint4 q = *(const uint4*)&tokL[mf * 16 + lr][e * 32 + kg * 8];
            af[mf] = __builtin_bit_cast(bf16x8, q);
        }
#pragma unroll
        for (int nf = 0; nf < 4; ++nf) {
            uint4 q = *(const uint4*)&wkq[(m0 + nf * 16 + lr) * 32 + kg * 8];
            bfr[nf] = __builtin_bit_cast(bf16x8, q);
        }
#pragma unroll
        for (int mf = 0; mf < 4; ++mf)
#pragma unroll
            for (int nf = 0; nf < 4; ++nf)
                acc[mf][nf] = __builtin_amdgcn_mfma_f32_16x16x32_bf16(
                    af[mf], bfr[nf], acc[mf][nf], 0, 0, 0);

        __syncthreads();   // all waves done reading wkq for eighth e
        if (e < 7) {
#pragma unroll
            for (int c = 0; c < 4; ++c)
                *(uint4*)&wkq[(c * 512 + t) * 8] = nst[c];
        }
        __syncthreads();   // eighth e+1 visible
    }

    // ---- epilogue: bias, block-wide LN stats ----
    float bbv[4], gv[4], bv[4];
#pragma unroll
    for (int nf = 0; nf < 4; ++nf) {
        int col = m0 + nf * 16 + lr;
        bbv[nf] = bb[col];
        gv[nf]  = gamma[col];
        bv[nf]  = beta[col];
    }

#pragma unroll
    for (int mf = 0; mf < 4; ++mf) {
#pragma unroll
        for (int r = 0; r < 4; ++r) {
            float sum = 0.0f, sq = 0.0f;
#pragma unroll
            for (int nf = 0; nf < 4; ++nf) {
                float v = acc[mf][nf][r] + bbv[nf];
                acc[mf][nf][r] = v;
                sum += v;
                sq  += v * v;
            }
#pragma unroll
            for (int off = 1; off < 16; off <<= 1) {
                sum += __shfl_xor(sum, off);
                sq  += __shfl_xor(sq, off);
            }
            if (lr == 0) {
                int row = mf * 16 + kg * 4 + r;
                red_sum[wave][row] = sum;
                red_sq[wave][row]  = sq;
            }
        }
    }
    __syncthreads();

    if (t < TSB) {
        float s = 0.0f, q = 0.0f;
#pragma unroll
        for (int w = 0; w < 8; ++w) { s += red_sum[w][t]; q += red_sq[w][t]; }
        float mean = s * (1.0f / D_MODEL);
        float var  = q * (1.0f / D_MODEL) - mean * mean;
        stats[0][t] = mean;
        stats[1][t] = rsqrtf(var + LN_EPS);
    }
    __syncthreads();

    // ---- normalize + store ----
#pragma unroll
    for (int mf = 0; mf < 4; ++mf) {
#pragma unroll
        for (int r = 0; r < 4; ++r) {
            int row = mf * 16 + kg * 4 + r;
            float mean = stats[0][row];
            float rstd = stats[1][row];
            float* op = out + ((size_t)b * S + s0 + row) * D_MODEL + m0 + lr;
#pragma unroll
            for (int nf = 0; nf < 4; ++nf)
                op[nf * 16] = (acc[mf][nf][r] - mean) * rstd * gv[nf] + bv[nf];
        }
    }
}

// ---------------------------------------------------------------------------
extern "C" void kernel_launch(void* const* d_in, const int* in_sizes, int n_in,
                              void* d_out, int out_size, void* d_ws, size_t ws_size,
                              hipStream_t stream)
{
    const int*   seq          = (const int*)d_in[0];
    const int*   king_id      = (const int*)d_in[1];
    const float* token_tables = (const float*)d_in[2];
    const float* Wb           = (const float*)d_in[3];
    const float* bb           = (const float*)d_in[4];
    const float* king_table   = (const float*)d_in[5];
    const float* gamma        = (const float*)d_in[6];
    const float* beta         = (const float*)d_in[7];
    float* out = (float*)d_out;

    unsigned short* Wk = (unsigned short*)d_ws;   // B*D_MODEL*D_EMB bf16 = 4 MB

    wk_mfma<<<dim3((D_MODEL * D_EMB) / 256), dim3(256), 0, stream>>>(
        Wb, king_table, king_id, Wk);
    gemm_ln_mfma<<<dim3(S / TSB, B), dim3(512), 0, stream>>>(
        seq, king_id, token_tables, Wk, bb, gamma, beta, out);
}